// Round 1
// baseline (122.645 us; speedup 1.0000x reference)
//
#include <hip/hip_runtime.h>

// Modulated deformable conv2d, fp32 in/out, bf16 MFMA core.
// B=4, C=64, H=W=128, O=64, K=3x3, stride=1, pad=1, dil=1, og=1, groups=1.
//
// Round 6: remove the per-tap LDS round-trip entirely. Each lane gathers the
// 4 bilinear corners for ITS OWN A-fragment slot (pixel m0+col, channels
// q*32+quad*8..+7) and blends in registers, feeding MFMA directly.
// This deletes 9 __syncthreads()/block (each a vmcnt(0)+lgkmcnt(0) drain that
// lockstepped 4 waves to the slowest gather) and all LDS traffic.
// Offset/mask scalar loads are software-pipelined one tap ahead.
// Fragment layouts (m89/m120-verified): A[m=lane&15][k=quad*8+j],
// B[k=quad*8+j][n=lane&15], D[row=quad*4+reg][col=lane&15].

#define BB 4
#define CC 64
#define HH 128
#define WW 128
#define OO 64
#define KHW 3
#define KK 9
#define HW (HH * WW)

typedef __bf16 bf16_t;
typedef bf16_t bf16x8 __attribute__((ext_vector_type(8)));
typedef float f32x4 __attribute__((ext_vector_type(4)));

// ---- x (NCHW fp32) -> xt (NHWC bf16), LDS-tiled transpose ----
__global__ __launch_bounds__(256) void nhwc_kernel(const float* __restrict__ x,
                                                   bf16_t* __restrict__ xt) {
    __shared__ float tile[64 * 65];
    const int t  = threadIdx.x;
    const int b  = blockIdx.x >> 8;
    const int p0 = (blockIdx.x & 255) << 6;
#pragma unroll
    for (int i = 0; i < 16; ++i) {
        int c = i * 4 + (t >> 6);
        int p = t & 63;
        tile[c * 65 + p] = x[(b * CC + c) * HW + p0 + p];  // coalesced read
    }
    __syncthreads();
#pragma unroll
    for (int i = 0; i < 16; ++i) {
        int p = i * 4 + (t >> 6);
        int c = t & 63;
        xt[(size_t)((b * HW) + p0 + p) * CC + c] = (bf16_t)tile[c * 65 + p];
    }
}

// ---- weight [O][C][3][3] fp32 -> B-fragment order bf16 ----
// wf element index: ((tap*2+q)*4+nt)*64*8 + lane*8 + j
//   holds W[o = nt*16 + (lane&15)][c = q*32 + (lane>>4)*8 + j][tap]
__global__ void wfrag_kernel(const float* __restrict__ w,
                             bf16_t* __restrict__ wf) {
    int i = blockIdx.x * blockDim.x + threadIdx.x;
    if (i >= OO * CC * KK) return;
    int j    = i & 7;
    int lane = (i >> 3) & 63;
    int nt   = (i >> 9) & 3;
    int q    = (i >> 11) & 1;
    int k    = i >> 12;
    int o = nt * 16 + (lane & 15);
    int c = q * 32 + ((lane >> 4) << 3) + j;
    wf[i] = (bf16_t)w[(o * CC + c) * KK + k];
}

__global__ __launch_bounds__(256) void deform_conv_mfma(
    const bf16_t* __restrict__ xt, const float* __restrict__ offset,
    const float* __restrict__ mask, const bf16x8* __restrict__ wf,
    const float* __restrict__ bias, float* __restrict__ out) {
    const int t    = threadIdx.x;
    const int b    = blockIdx.x >> 8;
    const int p0   = (blockIdx.x & 255) << 6;  // 64-pixel group
    const int lane = t & 63;
    const int wv   = t >> 6;
    const int m0   = wv << 4;                  // wave's 16-pixel strip
    const int col  = lane & 15;                // A-row m == pixel within strip
    const int quad = lane >> 4;
    const int rem  = p0 + m0 + col;            // this lane's pixel
    const int ho   = rem >> 7;
    const int wo   = rem & (WW - 1);
    const int cb   = quad << 3;                // channel sub-offset quad*8

    const bf16_t* xb  = xt + (size_t)b * HW * CC;
    const float* offp = offset + (size_t)b * (2 * KK) * HW + rem;
    const float* mp   = mask + (size_t)b * KK * HW + rem;

    f32x4 acc[4];
#pragma unroll
    for (int nt = 0; nt < 4; ++nt) acc[nt] = (f32x4){0.f, 0.f, 0.f, 0.f};

    // 1-deep pipeline on the offset/mask scalars: load tap k+1 before
    // computing tap k, so the offset->address->gather chain loses a hop.
    float offy = offp[0];
    float offx = offp[HW];
    float mm   = mp[0];

    for (int k = 0; k < KK; ++k) {
        float n_offy = 0.f, n_offx = 0.f, n_mm = 0.f;
        if (k < KK - 1) {
            n_offy = offp[(2 * k + 2) * HW];
            n_offx = offp[(2 * k + 3) * HW];
            n_mm   = mp[(k + 1) * HW];
        }

        // ---- per-lane bilinear setup for pixel `rem`, tap k ----
        float py = offy + (float)(k / KHW) + (float)(ho - 1);
        float px = offx + (float)(k % KHW) + (float)(wo - 1);
        float fy0 = floorf(py), fx0 = floorf(px);
        float ly = py - fy0, lx = px - fx0;
        int y0 = (int)fy0, x0 = (int)fx0;
        int y1 = y0 + 1, x1 = x0 + 1;
        bool vy0 = (y0 >= 0) && (y0 < HH);
        bool vy1 = (y1 >= 0) && (y1 < HH);
        bool vx0 = (x0 >= 0) && (x0 < WW);
        bool vx1 = (x1 >= 0) && (x1 < WW);
        int cy0 = min(max(y0, 0), HH - 1), cy1 = min(max(y1, 0), HH - 1);
        int cx0 = min(max(x0, 0), WW - 1), cx1 = min(max(x1, 0), WW - 1);
        float w0 = (vy0 && vx0) ? mm * (1.0f - ly) * (1.0f - lx) : 0.0f;
        float w1 = (vy0 && vx1) ? mm * (1.0f - ly) * lx : 0.0f;
        float w2 = (vy1 && vx0) ? mm * ly * (1.0f - lx) : 0.0f;
        float w3 = (vy1 && vx1) ? mm * ly * lx : 0.0f;

        // ---- gather this lane's own A-fragment channels (both q chunks) ----
        const bf16_t* b00 = xb + (size_t)(cy0 * WW + cx0) * CC + cb;
        const bf16_t* b01 = xb + (size_t)(cy0 * WW + cx1) * CC + cb;
        const bf16_t* b10 = xb + (size_t)(cy1 * WW + cx0) * CC + cb;
        const bf16_t* b11 = xb + (size_t)(cy1 * WW + cx1) * CC + cb;
        bf16x8 a00 = *(const bf16x8*)b00, c00 = *(const bf16x8*)(b00 + 32);
        bf16x8 a01 = *(const bf16x8*)b01, c01 = *(const bf16x8*)(b01 + 32);
        bf16x8 a10 = *(const bf16x8*)b10, c10 = *(const bf16x8*)(b10 + 32);
        bf16x8 a11 = *(const bf16x8*)b11, c11 = *(const bf16x8*)(b11 + 32);

        bf16x8 af0, af1;
#pragma unroll
        for (int i = 0; i < 8; ++i) {
            float v = w0 * (float)a00[i] + w1 * (float)a01[i] +
                      w2 * (float)a10[i] + w3 * (float)a11[i];
            af0[i] = (bf16_t)v;
        }
#pragma unroll
        for (int i = 0; i < 8; ++i) {
            float v = w0 * (float)c00[i] + w1 * (float)c01[i] +
                      w2 * (float)c10[i] + w3 * (float)c11[i];
            af1[i] = (bf16_t)v;
        }

        // ---- MFMA: 16 pixels x 64 outputs, K=64 split as q=0,1 ----
#pragma unroll
        for (int nt = 0; nt < 4; ++nt) {
            bf16x8 bfg = wf[(k * 8 + nt) * 64 + lane];            // q=0
            acc[nt] = __builtin_amdgcn_mfma_f32_16x16x32_bf16(
                af0, bfg, acc[nt], 0, 0, 0);
        }
#pragma unroll
        for (int nt = 0; nt < 4; ++nt) {
            bf16x8 bfg = wf[(k * 8 + 4 + nt) * 64 + lane];        // q=1
            acc[nt] = __builtin_amdgcn_mfma_f32_16x16x32_bf16(
                af1, bfg, acc[nt], 0, 0, 0);
        }

        offy = n_offy;
        offx = n_offx;
        mm   = n_mm;
    }

    // ---- epilogue: D[row=quad*4+reg][col] ; row -> pixel, col -> output ----
#pragma unroll
    for (int nt = 0; nt < 4; ++nt) {
        int o = nt * 16 + col;
        float bv = bias[o];
        f32x4 r = acc[nt];
        r.x += bv; r.y += bv; r.z += bv; r.w += bv;
        float* dst = out + (size_t)(b * OO + o) * HW + p0 + m0 + quad * 4;
        *(f32x4*)dst = r;  // 4 consecutive pixels, 16B aligned
    }
}

extern "C" void kernel_launch(void* const* d_in, const int* in_sizes, int n_in,
                              void* d_out, int out_size, void* d_ws,
                              size_t ws_size, hipStream_t stream) {
    const float* x      = (const float*)d_in[0];
    const float* offset = (const float*)d_in[1];
    const float* mask   = (const float*)d_in[2];
    const float* weight = (const float*)d_in[3];
    const float* bias   = (const float*)d_in[4];
    float* out = (float*)d_out;

    bf16_t* xt  = (bf16_t*)d_ws;                       // 4*16384*64*2 = 8 MB
    bf16_t* wfr = (bf16_t*)((char*)d_ws + (size_t)BB * HW * CC * 2);  // 72 KB

    nhwc_kernel<<<BB * (HW / 64), 256, 0, stream>>>(x, xt);

    int nw = OO * CC * KK;  // 36864
    wfrag_kernel<<<(nw + 255) / 256, 256, 0, stream>>>(weight, wfr);

    deform_conv_mfma<<<BB * (HW / 64), 256, 0, stream>>>(
        xt, offset, mask, (const bf16x8*)wfr, bias, out);
}